// Round 1
// 723.286 us; speedup vs baseline: 1.0279x; 1.0279x over previous
//
#include <hip/hip_runtime.h>
#include <math.h>

typedef unsigned int u32;
typedef short bf16x8 __attribute__((ext_vector_type(8)));   // 8 bf16 bit-patterns
typedef float f32x4 __attribute__((ext_vector_type(4)));

#define N0V 500000
#define N1V 50000
#define N2V 4096
#define E0V 1280000
#define E1V 40960
#define INF 128
#define HIDF 256
#define OUTF 47

// merged prep kernel block ranges (no more x->bf16 conversion: dense0 gathers f32 x directly)
#define HIST_BLOCKS 5160                       // 1,320,960 edges / 256
#define PACKW_BLOCKS 128

__device__ __forceinline__ u32 bf16rne(float f) {
  u32 u = __float_as_uint(f);
  return (u + 0x7fffu + ((u >> 16) & 1u)) >> 16;
}
__device__ __forceinline__ u32 pk2(float lo, float hi) {
  return bf16rne(lo) | (bf16rne(hi) << 16);
}

// ---------------- merged: dst histogram | W0 pack ----------------
__global__ __launch_bounds__(256) void prep_k(
    const int* __restrict__ dst0, const int* __restrict__ dst1,
    int* __restrict__ hist0, int* __restrict__ hist1,
    const float* __restrict__ Wl, const float* __restrict__ Wr,
    u32* __restrict__ Wf) {
  const int b = blockIdx.x;
  const int tid = threadIdx.x;
  if (b < HIST_BLOCKS) {
    int gid = b * 256 + tid;                 // < 1,320,960 exactly
    if (gid < E0V) {
      atomicAdd(&hist0[dst0[gid]], 1);
    } else {
      atomicAdd(&hist1[dst1[gid - E0V]], 1);
    }
  } else {
    // pack stacked [Wl;Wr] (256x256) into B-fragment order for 16x16x32 bf16:
    // lane holds B[k = s*32 + (lane>>4)*8 + j][n = t*16 + (lane&15)], j=0..7
    // layout: Wf[((t*8+s)*64 + lane)*8 + j]
    int gid = (b - HIST_BLOCKS) * 256 + tid;  // 0..32767
    int e0 = 2 * gid;
    int j = e0 & 7;
    int lane = (e0 >> 3) & 63;
    int sq = e0 >> 9;
    int s = sq & 7;
    int t = sq >> 3;
    int n = t * 16 + (lane & 15);
    int k0 = s * 32 + (lane >> 4) * 8 + j;
    float v0 = (k0 < 128) ? Wl[k0 * 256 + n] : Wr[(k0 - 128) * 256 + n];
    float v1 = (k0 + 1 < 128) ? Wl[(k0 + 1) * 256 + n] : Wr[(k0 + 1 - 128) * 256 + n];
    Wf[gid] = pk2(v0, v1);
  }
}

// ---------------- CSR build: prefix scan (single block) ----------------
__global__ __launch_bounds__(1024) void scan_k(
    const int* __restrict__ hist0, const int* __restrict__ hist1,
    int* __restrict__ off0, int* __restrict__ cur0,
    int* __restrict__ off1, int* __restrict__ cur1) {
  __shared__ int sums[1024];
  const int t = threadIdx.x;
  {
    const int N = 50000, C = 49;
    int lo = t * C;
    int hi = lo + C; if (hi > N) hi = N;
    int s = 0;
    for (int i = lo; i < hi; i++) s += hist0[i];
    sums[t] = s;
    __syncthreads();
    for (int off = 1; off < 1024; off <<= 1) {
      int v = (t >= off) ? sums[t - off] : 0;
      __syncthreads();
      sums[t] += v;
      __syncthreads();
    }
    int run = sums[t] - s;
    for (int i = lo; i < hi; i++) {
      off0[i] = run; cur0[i] = run;
      run += hist0[i];
    }
    if (t == 1023) off0[N] = sums[1023];
    __syncthreads();
  }
  {
    const int N = 4096, C = 4;
    int lo = t * C;
    int hi = lo + C; if (hi > N) hi = N;
    int s = 0;
    for (int i = lo; i < hi; i++) s += hist1[i];
    sums[t] = s;
    __syncthreads();
    for (int off = 1; off < 1024; off <<= 1) {
      int v = (t >= off) ? sums[t - off] : 0;
      __syncthreads();
      sums[t] += v;
      __syncthreads();
    }
    int run = sums[t] - s;
    for (int i = lo; i < hi; i++) {
      off1[i] = run; cur1[i] = run;
      run += hist1[i];
    }
    if (t == 1023) off1[N] = sums[1023];
  }
}

// ---------------- CSR build: scatter edge source ids ----------------
__global__ __launch_bounds__(256) void scatteridx_k(
    const int* __restrict__ src0, const int* __restrict__ dst0,
    const int* __restrict__ src1, const int* __restrict__ dst1,
    int* __restrict__ cur0, int* __restrict__ cur1,
    int* __restrict__ esrc0, int* __restrict__ esrc1) {
  int gid = blockIdx.x * 256 + threadIdx.x;
  if (gid < E0V) {
    int pos = atomicAdd(&cur0[dst0[gid]], 1);
    esrc0[pos] = src0[gid];
  } else if (gid < E0V + E1V) {
    int g = gid - E0V;
    int pos = atomicAdd(&cur1[dst1[g]], 1);
    esrc1[pos] = src1[g];
  }
}

// ---------------- layer 0: f32 float4 gather-mean + MFMA dense + relu ----------------
// 16 target rows/block, 4 waves; wave w aggregates rows w*4..w*4+3.
// Gather: 2 edges per wave-load step; lane = 32*(edge half) + w, loads float4
// (channels 4w..4w+3) of x row. Cross-half reduce via shfl_xor(32).
// Self-features in A_lds cols 128..255. Then 16x16x32 bf16 MFMA, K=256, N=256.
__global__ __launch_bounds__(256) void dense0_mfma(
    const float* __restrict__ x,
    const int* __restrict__ off0, const int* __restrict__ esrc0,
    const u32* __restrict__ Wf, const float* __restrict__ bl,
    float* __restrict__ h) {
  __shared__ __align__(16) unsigned short A_lds[16][264];
  const int tid = threadIdx.x;
  const int base = blockIdx.x * 16;
  const int wave = __builtin_amdgcn_readfirstlane(tid >> 6);  // wave-uniform
  const int lane = tid & 63;

  // self-features: thread -> row tid>>4, channels (tid&15)*8..+7
  {
    int r = tid >> 4;
    int cg = (tid & 15) * 8;
    const float4* xp = (const float4*)(x + (long long)(base + r) * INF + cg);
    float4 a = xp[0], b = xp[1];
    u32 o[4];
    o[0] = pk2(a.x, a.y); o[1] = pk2(a.z, a.w);
    o[2] = pk2(b.x, b.y); o[3] = pk2(b.z, b.w);
    *(uint4*)&A_lds[r][128 + cg] = *(const uint4*)o;
  }

  // gather-mean from f32 x: edge ids via wave-uniform (scalar) loads,
  // row data via float4 loads; 2 edges per step, 8-deep pipeline (16 edges in flight).
  const int half = lane >> 5;          // which of the 2 edges in a step
  const int w = lane & 31;             // float4 slot within row: channels 4w..4w+3
  const float4* xr = (const float4*)x; // row stride = 32 float4

  for (int q = 0; q < 4; q++) {
    int r = wave * 4 + q;
    int row = base + r;
    int s0 = __builtin_amdgcn_readfirstlane(off0[row]);
    int n  = __builtin_amdgcn_readfirstlane(off0[row + 1]) - s0;
    const int* e = esrc0 + s0;
    float ax = 0.f, ay = 0.f, az = 0.f, aw = 0.f;
    int j = 0;
    for (; j + 16 <= n; j += 16) {
      float4 v[8];
#pragma unroll
      for (int u = 0; u < 8; u++) {
        int sa = e[j + 2 * u];
        int sb = e[j + 2 * u + 1];
        int sid = half ? sb : sa;
        v[u] = xr[sid * 32 + w];
      }
#pragma unroll
      for (int u = 0; u < 8; u++) {
        ax += v[u].x; ay += v[u].y; az += v[u].z; aw += v[u].w;
      }
    }
    for (; j + 2 <= n; j += 2) {
      int sa = e[j];
      int sb = e[j + 1];
      int sid = half ? sb : sa;
      float4 v = xr[sid * 32 + w];
      ax += v.x; ay += v.y; az += v.z; aw += v.w;
    }
    if (j < n && half == 0) {
      float4 v = xr[e[j] * 32 + w];
      ax += v.x; ay += v.y; az += v.z; aw += v.w;
    }
    // combine the two edge-halves
    ax += __shfl_xor(ax, 32, 64);
    ay += __shfl_xor(ay, 32, 64);
    az += __shfl_xor(az, 32, 64);
    aw += __shfl_xor(aw, 32, 64);
    float rinv = 1.f / fmaxf((float)n, 1.f);
    if (half == 0) {
      uint2 p;
      p.x = pk2(ax * rinv, ay * rinv);
      p.y = pk2(az * rinv, aw * rinv);
      *(uint2*)&A_lds[r][4 * w] = p;   // channels 4w..4w+3 as bf16
    }
  }
  __syncthreads();

  // MFMA: A-frag m=lane&15, k = s*32 + (lane>>4)*8 + j
  const int m = lane & 15;
  const int quad = lane >> 4;
  f32x4 acc[4];
#pragma unroll
  for (int ti = 0; ti < 4; ti++) acc[ti] = (f32x4){0.f, 0.f, 0.f, 0.f};

  const bf16x8* Wf8 = (const bf16x8*)Wf;
  for (int s = 0; s < 8; s++) {
    bf16x8 af = *(const bf16x8*)&A_lds[m][s * 32 + quad * 8];
#pragma unroll
    for (int ti = 0; ti < 4; ti++) {
      int t = wave * 4 + ti;
      bf16x8 bfr = Wf8[(t * 8 + s) * 64 + lane];
      acc[ti] = __builtin_amdgcn_mfma_f32_16x16x32_bf16(af, bfr, acc[ti], 0, 0, 0);
    }
  }

  // C/D layout: col = lane&15, row = (lane>>4)*4 + reg
#pragma unroll
  for (int ti = 0; ti < 4; ti++) {
    int t = wave * 4 + ti;
    int n = t * 16 + m;
    float b = bl[n];
#pragma unroll
    for (int reg = 0; reg < 4; reg++) {
      int row = base + quad * 4 + reg;
      h[(long long)row * HIDF + n] = fmaxf(acc[ti][reg] + b, 0.0f);
    }
  }
}

// ---------------- layer 1: float4 gather-mean + dense + log_softmax ----------------
__global__ __launch_bounds__(64) void final_fused(
    const float* __restrict__ h, const int* __restrict__ off1,
    const int* __restrict__ esrc1, const float* __restrict__ Wl,
    const float* __restrict__ bl, const float* __restrict__ Wr,
    float* __restrict__ out) {
  __shared__ float a_s[256];
  __shared__ float h_s[256];
  const int i = blockIdx.x;
  const int lane = threadIdx.x;

  int s0 = __builtin_amdgcn_readfirstlane(off1[i]);
  int n  = __builtin_amdgcn_readfirstlane(off1[i + 1]) - s0;
  const int* e = esrc1 + s0;
  const float4* h4 = (const float4*)h;   // row = 64 float4
  float ax = 0.f, ay = 0.f, az = 0.f, aw = 0.f;
  int j = 0;
  for (; j + 4 <= n; j += 4) {
    float4 v[4];
#pragma unroll
    for (int u = 0; u < 4; u++) v[u] = h4[e[j + u] * 64 + lane];
#pragma unroll
    for (int u = 0; u < 4; u++) {
      ax += v[u].x; ay += v[u].y; az += v[u].z; aw += v[u].w;
    }
  }
  for (; j < n; j++) {
    float4 v = h4[e[j] * 64 + lane];
    ax += v.x; ay += v.y; az += v.z; aw += v.w;
  }
  float rinv = 1.f / fmaxf((float)n, 1.f);
  float4 am; am.x = ax * rinv; am.y = ay * rinv; am.z = az * rinv; am.w = aw * rinv;
  ((float4*)a_s)[lane] = am;             // a_s[k] = mean channel k
  ((float4*)h_s)[lane] = h4[i * 64 + lane];
  __syncthreads();

  float val = -INFINITY;
  if (lane < OUTF) {
    float acc = bl[lane];
#pragma unroll 4
    for (int k = 0; k < 256; k++)
      acc += a_s[k] * Wl[k * OUTF + lane] + h_s[k] * Wr[k * OUTF + lane];
    val = acc;
  }

  float mx = val;
  for (int off = 32; off >= 1; off >>= 1) mx = fmaxf(mx, __shfl_xor(mx, off, 64));
  float ex = (lane < OUTF) ? expf(val - mx) : 0.0f;
  float ssum = ex;
  for (int off = 32; off >= 1; off >>= 1) ssum += __shfl_xor(ssum, off, 64);

  if (lane < OUTF) out[i * OUTF + lane] = val - mx - logf(ssum);
}

extern "C" void kernel_launch(void* const* d_in, const int* in_sizes, int n_in,
                              void* d_out, int out_size, void* d_ws, size_t ws_size,
                              hipStream_t stream) {
  const float* x   = (const float*)d_in[0];
  const float* Wl0 = (const float*)d_in[1];
  const float* bl0 = (const float*)d_in[2];
  const float* Wr0 = (const float*)d_in[3];
  const float* Wl1 = (const float*)d_in[4];
  const float* bl1 = (const float*)d_in[5];
  const float* Wr1 = (const float*)d_in[6];
  const int* src0  = (const int*)d_in[7];
  const int* dst0  = (const int*)d_in[8];
  const int* src1  = (const int*)d_in[9];
  const int* dst1  = (const int*)d_in[10];
  float* out = (float*)d_out;

  // workspace layout (bytes):
  //   hist0 @ 0           200,000
  //   hist1 @ 200,064      16,384   (memset covers [0, 216,448))
  //   off0  @ 216,576     200,004
  //   cur0  @ 416,768     200,000
  //   off1  @ 616,960      16,388
  //   cur1  @ 633,600      16,384
  //   esrc0 @ 650,240   5,120,000
  //   esrc1 @ 5,770,240   163,840
  //   h     @ 5,934,080  51,200,000  (end 57,134,080)
  //   Wf0   @ 57,134,080    131,072  (end 57,265,152)
  char* ws = (char*)d_ws;
  int* hist0 = (int*)(ws);
  int* hist1 = (int*)(ws + 200064);
  int* off0  = (int*)(ws + 216576);
  int* cur0  = (int*)(ws + 416768);
  int* off1  = (int*)(ws + 616960);
  int* cur1  = (int*)(ws + 633600);
  int* esrc0 = (int*)(ws + 650240);
  int* esrc1 = (int*)(ws + 5770240);
  float* h   = (float*)(ws + 5934080);
  u32* Wf0   = (u32*)(ws + 57134080);

  hipMemsetAsync(ws, 0, 216448, stream);

  prep_k<<<HIST_BLOCKS + PACKW_BLOCKS, 256, 0, stream>>>(
      dst0, dst1, hist0, hist1, Wl0, Wr0, Wf0);
  scan_k<<<1, 1024, 0, stream>>>(hist0, hist1, off0, cur0, off1, cur1);
  scatteridx_k<<<(E0V + E1V + 255) / 256, 256, 0, stream>>>(
      src0, dst0, src1, dst1, cur0, cur1, esrc0, esrc1);
  dense0_mfma<<<N1V / 16, 256, 0, stream>>>(x, off0, esrc0, Wf0, bl0, h);
  final_fused<<<N2V, 64, 0, stream>>>(h, off1, esrc1, Wl1, bl1, Wr1, out);
}